// Round 2
// 758.393 us; speedup vs baseline: 1.0056x; 1.0056x over previous
//
#include <hip/hip_runtime.h>

// Problem constants:
//   B = 2, T = 1'000'000, C = 16, G = 500'000, K = 9
// out[b, g, k, c] = textures[b, group_idx[g, k], c]
//
// Two-phase strategy:
//   Phase A: repack textures [B][T][C] -> packed [T][B][C] in workspace, so each
//            texel t occupies ONE fully-used 128B record (both batches adjacent).
//            128 MB, fits in the 256 MB Infinity Cache; cached stores keep it warm.
//   Phase B: gather. 8 lanes per (g,k): one full 128B line read per group-texel,
//            zero over-fetch, nontemporal streaming writes to out.

typedef float f4 __attribute__((ext_vector_type(4)));

constexpr long long T_ = 1000000;
constexpr int       C4 = 4;                  // float4 chunks per texel row (C=16)
constexpr long long GK = 500000LL * 9;       // 4.5M flattened (g,k)
constexpr long long PACKED_F4 = T_ * 2 * C4; // 8M float4 = 128 MB

// ---- Phase A: packed[t*8 + b*4 + c4] = textures[(b*T + t)*4 + c4] ----
// Wave access: reads = two contiguous 512B segments (one per batch plane),
// writes = one contiguous 1KB segment. Fully coalesced both sides.
__global__ __launch_bounds__(256) void
TMSCNN_repack_kernel(const f4* __restrict__ textures, f4* __restrict__ packed)
{
    const unsigned tid = blockIdx.x * blockDim.x + threadIdx.x;  // 8M threads
    if (tid >= (unsigned)PACKED_F4) return;
    const unsigned j   = tid & 7;      // b*4 + c4
    const unsigned t   = tid >> 3;
    const unsigned b   = j >> 2;
    const unsigned c4  = j & 3;
    const long long src = ((long long)b * T_ + (long long)t) * C4 + c4;
    packed[tid] = textures[src];       // cached store: want it resident in L2/L3
}

// ---- Phase B: 8 lanes per (g,k); lane j reads packed[idx*8 + j] (one 128B line
// per 8-lane group, 100% consumed). Store pattern per wave: b=0 lanes form one
// contiguous 512B run, b=1 lanes another. ----
__global__ __launch_bounds__(256) void
TMSCNN_gather_kernel(const f4* __restrict__ packed,
                     const int* __restrict__ group_idx,
                     f4*       __restrict__ out)
{
    const unsigned tid = blockIdx.x * blockDim.x + threadIdx.x;  // 36M threads
    if (tid >= (unsigned)(GK * 8)) return;
    const unsigned j   = tid & 7;      // b*4 + c4
    const unsigned gk  = tid >> 3;
    const unsigned b   = j >> 2;
    const unsigned c4  = j & 3;

    // group_idx is an 18MB single-use stream: don't let it pollute caches.
    const int idx = __builtin_nontemporal_load(&group_idx[gk]);

    const f4 v = packed[(long long)idx * 8 + j];   // cached: L3 serves 4.5x reuse

    const long long dst = (long long)b * (GK * C4) + (long long)gk * C4 + c4;
    __builtin_nontemporal_store(v, &out[dst]);     // streaming: skip cache pollution
}

// ---- Fallback (workspace too small): previous single-pass kernel ----
__global__ __launch_bounds__(256) void
TMSCNN_direct_kernel(const f4* __restrict__ textures,
                     const int* __restrict__ group_idx,
                     f4*       __restrict__ out)
{
    const unsigned tid = blockIdx.x * blockDim.x + threadIdx.x;
    if (tid >= (unsigned)(GK * C4)) return;
    const int          c4 = tid & 3;
    const unsigned int gk = tid >> 2;

    const int idx = group_idx[gk];
    const long long src0 = (long long)idx * C4 + c4;
    const long long src1 = (T_ + (long long)idx) * C4 + c4;
    const f4 v0 = textures[src0];
    const f4 v1 = textures[src1];
    const long long dst0 = (long long)gk * C4 + c4;
    const long long dst1 = (GK + (long long)gk) * C4 + c4;
    __builtin_nontemporal_store(v0, &out[dst0]);
    __builtin_nontemporal_store(v1, &out[dst1]);
}

extern "C" void kernel_launch(void* const* d_in, const int* in_sizes, int n_in,
                              void* d_out, int out_size, void* d_ws, size_t ws_size,
                              hipStream_t stream) {
    // d_in[0] = mesh_ids  (int32, unused by the reference)
    // d_in[1] = textures  (float32, [B, T, C])
    // d_in[2] = group_idx (int32,   [G, K])
    const f4*  textures  = (const f4*)d_in[1];
    const int* group_idx = (const int*)d_in[2];
    f4*        out       = (f4*)d_out;

    const int threads = 256;
    const size_t packed_bytes = (size_t)PACKED_F4 * sizeof(f4);  // 128 MB

    if (d_ws != nullptr && ws_size >= packed_bytes) {
        f4* packed = (f4*)d_ws;

        const long long nA = PACKED_F4;   // 8,000,000  -> 31,250 blocks
        const long long nB = GK * 8;      // 36,000,000 -> 140,625 blocks

        TMSCNN_repack_kernel<<<(int)((nA + threads - 1) / threads), threads, 0, stream>>>(
            textures, packed);
        TMSCNN_gather_kernel<<<(int)((nB + threads - 1) / threads), threads, 0, stream>>>(
            packed, group_idx, out);
    } else {
        const unsigned long long total = (unsigned long long)GK * C4;  // 18M
        TMSCNN_direct_kernel<<<(int)((total + threads - 1) / threads), threads, 0, stream>>>(
            textures, group_idx, out);
    }
}

// Round 3
// 756.772 us; speedup vs baseline: 1.0078x; 1.0021x over previous
//
#include <hip/hip_runtime.h>

// Problem constants:
//   B = 2, T = 1'000'000, C = 16, G = 500'000, K = 9
// out[b, g, k, c] = textures[b, group_idx[g, k], c]
//
// Strategy: repack textures [B][T][C] -> packed [T][B][C] so each texel is ONE
// fully-used 128B record (both batches adjacent). Gather then reads exactly one
// full line per (g,k): no over-fetch, half the random requests, and the 128MB
// packed array is an L3-stable working set.
//
// Scratch: prefer d_ws if >=128MB. Otherwise use the LAST 128MB of `out` as
// scratch, with race-free ordering:
//   K1  repack -> scratch (= out f4 [28M,36M) = b=1, gk in [2.5M,4.5M) region)
//   K2a gather gk<2.5M (both b) from packed      -> writes outside scratch only
//   K2b gather b=0, gk>=2.5M from packed b0-half -> writes outside scratch only
//   K3  tail  b=1, gk>=2.5M from textures direct -> overwrites scratch (reads
//       only textures; all packed readers already retired by stream order)

typedef float f4 __attribute__((ext_vector_type(4)));

constexpr long long T_  = 1000000;
constexpr int       C4  = 4;                  // float4 chunks per texel row
constexpr long long GK  = 500000LL * 9;       // 4.5M flattened (g,k)
constexpr long long PACKED_F4 = T_ * 2 * C4;  // 8M f4 = 128 MB
constexpr long long OUT_F4    = 2 * GK * C4;  // 36M f4 = 576 MB
constexpr long long SCRATCH_OFF_F4 = OUT_F4 - PACKED_F4;   // 28M f4
constexpr long long GK_SPLIT = 2500000;       // gk threshold covered by K2a

// ---- K1: packed[t*8 + b*4 + c4] = textures[(b*T + t)*4 + c4] ----
__global__ __launch_bounds__(256) void
TMSCNN_repack_kernel(const f4* __restrict__ textures, f4* __restrict__ packed)
{
    const unsigned tid = blockIdx.x * blockDim.x + threadIdx.x;  // 8M threads
    if (tid >= (unsigned)PACKED_F4) return;
    const unsigned j  = tid & 7;       // b*4 + c4
    const unsigned t  = tid >> 3;
    const unsigned b  = j >> 2;
    const unsigned c4 = j & 3;
    const long long src = ((long long)b * T_ + (long long)t) * C4 + c4;
    packed[tid] = textures[src];       // cached store: keep packed L3-resident
}

// ---- K2a: 8 lanes per (g,k), one full 128B line per group-texel. Grid size
// selects the gk range: n threads covers gk in [0, n/8). ----
__global__ __launch_bounds__(256) void
TMSCNN_gather_full_kernel(const f4* __restrict__ packed,
                          const int* __restrict__ group_idx,
                          f4*       __restrict__ out,
                          unsigned long long n)
{
    const unsigned tid = blockIdx.x * blockDim.x + threadIdx.x;
    if (tid >= n) return;
    const unsigned j  = tid & 7;       // b*4 + c4
    const unsigned gk = tid >> 3;
    const unsigned b  = j >> 2;
    const unsigned c4 = j & 3;

    const int idx = __builtin_nontemporal_load(&group_idx[gk]);
    const f4 v = packed[(long long)idx * 8 + j];

    const long long dst = (long long)b * (GK * C4) + (long long)gk * C4 + c4;
    __builtin_nontemporal_store(v, &out[dst]);
}

// ---- K2b: b=0 only, gk in [GK_SPLIT, GK). Reads b0 half of packed records. ----
__global__ __launch_bounds__(256) void
TMSCNN_gather_b0_kernel(const f4* __restrict__ packed,
                        const int* __restrict__ group_idx,
                        f4*       __restrict__ out)
{
    const unsigned tid = blockIdx.x * blockDim.x + threadIdx.x;  // 8M threads
    if (tid >= (unsigned)((GK - GK_SPLIT) * C4)) return;
    const unsigned c4 = tid & 3;
    const long long gk = GK_SPLIT + (long long)(tid >> 2);

    const int idx = __builtin_nontemporal_load(&group_idx[gk]);
    const f4 v = packed[(long long)idx * 8 + c4];          // b=0 half

    const long long dst = gk * C4 + c4;                    // in [10M, 18M) f4
    __builtin_nontemporal_store(v, &out[dst]);
}

// ---- K3: b=1, gk in [GK_SPLIT, GK). Reads textures directly (never packed),
// writes land exactly on the scratch region. ----
__global__ __launch_bounds__(256) void
TMSCNN_gather_tail_kernel(const f4* __restrict__ textures,
                          const int* __restrict__ group_idx,
                          f4*       __restrict__ out)
{
    const unsigned tid = blockIdx.x * blockDim.x + threadIdx.x;  // 8M threads
    if (tid >= (unsigned)((GK - GK_SPLIT) * C4)) return;
    const unsigned c4 = tid & 3;
    const long long gk = GK_SPLIT + (long long)(tid >> 2);

    const int idx = __builtin_nontemporal_load(&group_idx[gk]);
    const f4 v = textures[(T_ + (long long)idx) * C4 + c4];      // b=1 plane

    const long long dst = GK * C4 + gk * C4 + c4;          // in [28M, 36M) f4
    __builtin_nontemporal_store(v, &out[dst]);
}

extern "C" void kernel_launch(void* const* d_in, const int* in_sizes, int n_in,
                              void* d_out, int out_size, void* d_ws, size_t ws_size,
                              hipStream_t stream) {
    // d_in[0] = mesh_ids (unused); d_in[1] = textures [B,T,C]; d_in[2] = group_idx [G,K]
    const f4*  textures  = (const f4*)d_in[1];
    const int* group_idx = (const int*)d_in[2];
    f4*        out       = (f4*)d_out;

    const int threads = 256;
    const size_t packed_bytes = (size_t)PACKED_F4 * sizeof(f4);  // 128 MB

    if (d_ws != nullptr && ws_size >= packed_bytes) {
        // Clean path: scratch in workspace, single uniform gather.
        f4* packed = (f4*)d_ws;
        TMSCNN_repack_kernel<<<(int)(PACKED_F4 / threads), threads, 0, stream>>>(
            textures, packed);
        const unsigned long long nB = (unsigned long long)GK * 8;  // 36M
        TMSCNN_gather_full_kernel<<<(int)(nB / threads), threads, 0, stream>>>(
            packed, group_idx, out, nB);
    } else {
        // Scratch-in-out path: tail 128MB of `out` holds packed until K3.
        f4* packed = out + SCRATCH_OFF_F4;

        TMSCNN_repack_kernel<<<(int)(PACKED_F4 / threads), threads, 0, stream>>>(
            textures, packed);

        const unsigned long long n2a = (unsigned long long)GK_SPLIT * 8;  // 20M
        TMSCNN_gather_full_kernel<<<(int)(n2a / threads), threads, 0, stream>>>(
            packed, group_idx, out, n2a);

        const long long n2b = (GK - GK_SPLIT) * C4;  // 8M
        TMSCNN_gather_b0_kernel<<<(int)(n2b / threads), threads, 0, stream>>>(
            packed, group_idx, out);

        TMSCNN_gather_tail_kernel<<<(int)(n2b / threads), threads, 0, stream>>>(
            textures, group_idx, out);
    }
}